// Round 1
// baseline (1762.770 us; speedup 1.0000x reference)
//
#include <hip/hip_runtime.h>

#define NUSER 100000
#define NITEM 50000
#define NNODE 150000
#define DIM 64
#define FEAT 4096
#define H1 256   // 4*DIM

typedef short bf16x8 __attribute__((ext_vector_type(8)));
typedef float f32x4 __attribute__((ext_vector_type(4)));

__device__ inline unsigned short f2bf(float f){
    unsigned u = __float_as_uint(f);
    return (unsigned short)((u + 0x7fffu + ((u >> 16) & 1u)) >> 16);  // RNE
}

// ---------------- W1 [FEAT,H1] fp32 -> Wt [H1,FEAT] bf16 (k-contiguous) -------------
__global__ void k_transpose_w1(const float* __restrict__ W1, unsigned short* __restrict__ Wt){
    int tid = blockIdx.x * 256 + threadIdx.x;     // H1*FEAT = 1,048,576 threads
    int n = tid >> 12;                             // / FEAT
    int k = tid & (FEAT - 1);
    Wt[(size_t)n * FEAT + k] = f2bf(W1[(size_t)k * H1 + n]);
}

// ---------------- degree count over col ----------------
__global__ void k_count(const int* __restrict__ col, int E, int* __restrict__ cnt){
    int e = blockIdx.x * 256 + threadIdx.x;
    if (e < E) atomicAdd(&cnt[col[e]], 1);
}

__global__ void k_dis(const int* __restrict__ cnt, float* __restrict__ dis){
    int i = blockIdx.x * 256 + threadIdx.x;
    if (i < NNODE){ int c = cnt[i]; dis[i] = c > 0 ? 1.0f / sqrtf((float)c) : 0.0f; }
}

// ---------------- 3-kernel exclusive scan of cnt -> off, cur ----------------
__global__ void k_scan1(const int* __restrict__ cnt, int* __restrict__ bsum){
    __shared__ int s[256];
    int i = blockIdx.x * 256 + threadIdx.x;
    int v = (i < NNODE) ? cnt[i] : 0;
    s[threadIdx.x] = v; __syncthreads();
    for (int o = 128; o > 0; o >>= 1){
        if (threadIdx.x < o) s[threadIdx.x] += s[threadIdx.x + o];
        __syncthreads();
    }
    if (threadIdx.x == 0) bsum[blockIdx.x] = s[0];
}

__global__ void k_scan2(const int* __restrict__ bsum, int* __restrict__ bscan, int nb){
    __shared__ int s[1024];
    int tid = threadIdx.x;
    int v = (tid < nb) ? bsum[tid] : 0;
    s[tid] = v; __syncthreads();
    for (int o = 1; o < 1024; o <<= 1){
        int t = 0; if (tid >= o) t = s[tid - o];
        __syncthreads(); s[tid] += t; __syncthreads();
    }
    if (tid < nb) bscan[tid] = s[tid] - v;   // exclusive
}

__global__ void k_scan3(const int* __restrict__ cnt, const int* __restrict__ bscan,
                        int* __restrict__ off, int* __restrict__ cur){
    __shared__ int s[256];
    int tid = threadIdx.x;
    int i = blockIdx.x * 256 + tid;
    int v = (i < NNODE) ? cnt[i] : 0;
    s[tid] = v; __syncthreads();
    for (int o = 1; o < 256; o <<= 1){
        int t = 0; if (tid >= o) t = s[tid - o];
        __syncthreads(); s[tid] += t; __syncthreads();
    }
    int excl = s[tid] - v + bscan[blockIdx.x];
    if (i < NNODE){ off[i] = excl; cur[i] = excl; }
}

__global__ void k_scatter(const int* __restrict__ row, const int* __restrict__ col, int E,
                          const float* __restrict__ dis, int* __restrict__ cur,
                          int* __restrict__ csr_src, float* __restrict__ csr_w){
    int e = blockIdx.x * 256 + threadIdx.x;
    if (e < E){
        int c = col[e], r = row[e];
        int p = atomicAdd(&cur[c], 1);
        csr_src[p] = r;
        csr_w[p] = dis[r] * dis[c];
    }
}

// ---------------- GEMM1: H = leaky_relu(features @ W1 + b1) ----------------
// A fp32 [50000,4096], Bt bf16 [256,4096] (pre-transposed, k-contiguous).
// Block 256 thr = 4 waves (2x2), tile 128x128, BK=32, double-buffered LDS,
// A converted fp32->bf16 inline. LDS row stride 40 (pad +8 bf16 = 16B, keeps b128 align,
// spreads banks: 20 dwords/row -> 2-way conflict = free).
__global__ __launch_bounds__(256) void k_gemm1(const float* __restrict__ A,
                                               const unsigned short* __restrict__ Bt,
                                               const float* __restrict__ b1,
                                               float* __restrict__ H){
    __shared__ unsigned short As[2][128 * 40];
    __shared__ unsigned short Bs[2][128 * 40];
    const int tid = threadIdx.x;
    const int m0 = blockIdx.x * 128;
    const int n0 = blockIdx.y * 128;

    // staging assignment: 2 threads per row, 16 elems each
    const int r  = tid >> 1;
    const int kh = (tid & 1) * 16;
    int mg = m0 + r; if (mg >= NITEM) mg = NITEM - 1;   // clamp (dup load, store guarded)
    const float*          aptr = A  + (size_t)mg * FEAT + kh;
    const unsigned short* bptr = Bt + (size_t)(n0 + r) * FEAT + kh;

    const int wid = tid >> 6, lane = tid & 63;
    const int wm = (wid & 1) * 64, wn = (wid >> 1) * 64;
    const int m16 = lane & 15, q = lane >> 4;

    f32x4 acc[4][4];
#pragma unroll
    for (int i = 0; i < 4; i++)
#pragma unroll
        for (int j = 0; j < 4; j++)
            acc[i][j] = (f32x4){0.f, 0.f, 0.f, 0.f};

    float4 af[4];
    bf16x8 br[2];

    // prologue: load tile 0 and stage
    {
        const float* ap = aptr;
        af[0] = *(const float4*)(ap);      af[1] = *(const float4*)(ap + 4);
        af[2] = *(const float4*)(ap + 8);  af[3] = *(const float4*)(ap + 12);
        const bf16x8* bp = (const bf16x8*)bptr;
        br[0] = bp[0]; br[1] = bp[1];
        bf16x8 v0, v1;
        v0[0]=(short)f2bf(af[0].x); v0[1]=(short)f2bf(af[0].y); v0[2]=(short)f2bf(af[0].z); v0[3]=(short)f2bf(af[0].w);
        v0[4]=(short)f2bf(af[1].x); v0[5]=(short)f2bf(af[1].y); v0[6]=(short)f2bf(af[1].z); v0[7]=(short)f2bf(af[1].w);
        v1[0]=(short)f2bf(af[2].x); v1[1]=(short)f2bf(af[2].y); v1[2]=(short)f2bf(af[2].z); v1[3]=(short)f2bf(af[2].w);
        v1[4]=(short)f2bf(af[3].x); v1[5]=(short)f2bf(af[3].y); v1[6]=(short)f2bf(af[3].z); v1[7]=(short)f2bf(af[3].w);
        unsigned short* aw = &As[0][r * 40 + kh];
        *(bf16x8*)aw = v0; *(bf16x8*)(aw + 8) = v1;
        unsigned short* bw = &Bs[0][r * 40 + kh];
        *(bf16x8*)bw = br[0]; *(bf16x8*)(bw + 8) = br[1];
    }
    __syncthreads();

    const int NT = FEAT / 32;  // 128
    for (int kt = 0; kt < NT; ++kt){
        const int cur = kt & 1;
        if (kt + 1 < NT){
            const float* ap = aptr + (kt + 1) * 32;
            af[0] = *(const float4*)(ap);      af[1] = *(const float4*)(ap + 4);
            af[2] = *(const float4*)(ap + 8);  af[3] = *(const float4*)(ap + 12);
            const bf16x8* bp = (const bf16x8*)(bptr + (kt + 1) * 32);
            br[0] = bp[0]; br[1] = bp[1];
        }
        bf16x8 afr[4], bfr[4];
#pragma unroll
        for (int i = 0; i < 4; i++){
            afr[i] = *(const bf16x8*)&As[cur][(wm + i * 16 + m16) * 40 + q * 8];
            bfr[i] = *(const bf16x8*)&Bs[cur][(wn + i * 16 + m16) * 40 + q * 8];
        }
#pragma unroll
        for (int mi = 0; mi < 4; mi++)
#pragma unroll
            for (int ni = 0; ni < 4; ni++)
                acc[mi][ni] = __builtin_amdgcn_mfma_f32_16x16x32_bf16(afr[mi], bfr[ni], acc[mi][ni], 0, 0, 0);
        if (kt + 1 < NT){
            bf16x8 v0, v1;
            v0[0]=(short)f2bf(af[0].x); v0[1]=(short)f2bf(af[0].y); v0[2]=(short)f2bf(af[0].z); v0[3]=(short)f2bf(af[0].w);
            v0[4]=(short)f2bf(af[1].x); v0[5]=(short)f2bf(af[1].y); v0[6]=(short)f2bf(af[1].z); v0[7]=(short)f2bf(af[1].w);
            v1[0]=(short)f2bf(af[2].x); v1[1]=(short)f2bf(af[2].y); v1[2]=(short)f2bf(af[2].z); v1[3]=(short)f2bf(af[2].w);
            v1[4]=(short)f2bf(af[3].x); v1[5]=(short)f2bf(af[3].y); v1[6]=(short)f2bf(af[3].z); v1[7]=(short)f2bf(af[3].w);
            unsigned short* aw = &As[cur ^ 1][r * 40 + kh];
            *(bf16x8*)aw = v0; *(bf16x8*)(aw + 8) = v1;
            unsigned short* bw = &Bs[cur ^ 1][r * 40 + kh];
            *(bf16x8*)bw = br[0]; *(bf16x8*)(bw + 8) = br[1];
        }
        __syncthreads();
    }

    // epilogue: C/D layout col=lane&15, row=q*4+reg
#pragma unroll
    for (int ni = 0; ni < 4; ni++){
        const int n = n0 + wn + ni * 16 + m16;
        const float bias = b1[n];
#pragma unroll
        for (int mi = 0; mi < 4; mi++){
#pragma unroll
            for (int rr = 0; rr < 4; rr++){
                int m = m0 + wm + mi * 16 + q * 4 + rr;
                if (m < NITEM){
                    float v = acc[mi][ni][rr] + bias;
                    H[(size_t)m * H1 + n] = v > 0.f ? v : 0.01f * v;
                }
            }
        }
    }
}

// ---------------- GEMM2 + bias + L2-normalize -> x rows [NUSER..NNODE) ----------------
__global__ void k_gemm2_norm(const float* __restrict__ Hm, const float* __restrict__ W2,
                             const float* __restrict__ b2, float* __restrict__ out1){
    int wid = threadIdx.x >> 6, lane = threadIdx.x & 63;
    int m = blockIdx.x * 4 + wid;
    if (m >= NITEM) return;
    m = __builtin_amdgcn_readfirstlane(m);
    const float* hr = Hm + (size_t)m * H1;
    float acc = 0.f;
#pragma unroll 8
    for (int k = 0; k < H1; k++)
        acc = fmaf(hr[k], W2[k * DIM + lane], acc);
    acc += b2[lane];
    float ss = acc * acc;
    for (int o = 32; o > 0; o >>= 1) ss += __shfl_xor(ss, o);
    float den = fmaxf(sqrtf(ss), 1e-12f);
    out1[(size_t)(NUSER + m) * DIM + lane] = acc / den;
}

// ---------------- preference: normalize -> x rows [0..NUSER), raw copy -> out2 --------
__global__ void k_pref_norm(const float* __restrict__ P, float* __restrict__ out1,
                            float* __restrict__ out2){
    int wid = threadIdx.x >> 6, lane = threadIdx.x & 63;
    int m = blockIdx.x * 4 + wid;
    if (m >= NUSER) return;
    float v = P[(size_t)m * DIM + lane];
    out2[(size_t)m * DIM + lane] = v;
    float ss = v * v;
    for (int o = 32; o > 0; o >>= 1) ss += __shfl_xor(ss, o);
    float den = fmaxf(sqrtf(ss), 1e-12f);
    out1[(size_t)m * DIM + lane] = v / den;
}

// ---------------- CSR gather conv: h[t] = sum_e w[e]*x[src[e]] ----------------
__global__ void k_conv(const float* __restrict__ x, const int* __restrict__ off,
                       const int* __restrict__ cnt, const int* __restrict__ src,
                       const float* __restrict__ w, float* __restrict__ hout){
    int wid = threadIdx.x >> 6, lane = threadIdx.x & 63;
    int t = blockIdx.x * 4 + wid;
    if (t >= NNODE) return;
    int base = __builtin_amdgcn_readfirstlane(off[t]);
    int c    = __builtin_amdgcn_readfirstlane(cnt[t]);
    float acc = 0.f;
    for (int j = 0; j < c; j++){
        int s = src[base + j];
        float wt = w[base + j];
        acc = fmaf(wt, x[(size_t)s * DIM + lane], acc);
    }
    hout[(size_t)t * DIM + lane] = acc;
}

// ---------------- conv2 fused with x_hat = x + h + h1 (in-place on out1) -------------
__global__ void k_conv_final(const float* __restrict__ h, const int* __restrict__ off,
                             const int* __restrict__ cnt, const int* __restrict__ src,
                             const float* __restrict__ w, float* __restrict__ out1){
    int wid = threadIdx.x >> 6, lane = threadIdx.x & 63;
    int t = blockIdx.x * 4 + wid;
    if (t >= NNODE) return;
    int base = __builtin_amdgcn_readfirstlane(off[t]);
    int c    = __builtin_amdgcn_readfirstlane(cnt[t]);
    float acc = 0.f;
    for (int j = 0; j < c; j++){
        int s = src[base + j];
        float wt = w[base + j];
        acc = fmaf(wt, h[(size_t)s * DIM + lane], acc);
    }
    size_t idx = (size_t)t * DIM + lane;
    out1[idx] = out1[idx] + h[idx] + acc;   // x + h + h1 (own row only -> no hazard)
}

extern "C" void kernel_launch(void* const* d_in, const int* in_sizes, int n_in,
                              void* d_out, int out_size, void* d_ws, size_t ws_size,
                              hipStream_t stream){
    const int*   edge     = (const int*)d_in[0];
    const float* features = (const float*)d_in[1];
    const float* pref     = (const float*)d_in[2];
    const float* W1       = (const float*)d_in[3];
    const float* b1       = (const float*)d_in[4];
    const float* W2       = (const float*)d_in[5];
    const float* b2       = (const float*)d_in[6];
    const int E = in_sizes[0] / 2;
    const int* row = edge;
    const int* col = edge + E;

    char* p = (char*)d_ws;
    auto alloc = [&](size_t bytes) -> char* {
        char* q = p; p += (bytes + 255) & ~(size_t)255; return q;
    };
    unsigned short* Wt   = (unsigned short*)alloc((size_t)H1 * FEAT * 2);
    float* Hm            = (float*)alloc((size_t)NITEM * H1 * 4);
    float* h             = (float*)alloc((size_t)NNODE * DIM * 4);
    float* dis           = (float*)alloc((size_t)NNODE * 4);
    int*   cnt           = (int*)alloc((size_t)NNODE * 4);
    int*   off           = (int*)alloc((size_t)NNODE * 4);
    int*   cur           = (int*)alloc((size_t)NNODE * 4);
    int*   bsum          = (int*)alloc(4096);
    int*   bscan         = (int*)alloc(4096);
    int*   csr_src       = (int*)alloc((size_t)E * 4);
    float* csr_w         = (float*)alloc((size_t)E * 4);

    float* out1 = (float*)d_out;                    // x_hat [NNODE, DIM]
    float* out2 = out1 + (size_t)NNODE * DIM;       // preference copy [NUSER, DIM]

    hipMemsetAsync(cnt, 0, (size_t)NNODE * 4, stream);

    k_transpose_w1<<<(H1 * FEAT) / 256, 256, 0, stream>>>(W1, Wt);
    k_count<<<(E + 255) / 256, 256, 0, stream>>>(col, E, cnt);
    k_dis<<<(NNODE + 255) / 256, 256, 0, stream>>>(cnt, dis);
    const int nb = (NNODE + 255) / 256;   // 586
    k_scan1<<<nb, 256, 0, stream>>>(cnt, bsum);
    k_scan2<<<1, 1024, 0, stream>>>(bsum, bscan, nb);
    k_scan3<<<nb, 256, 0, stream>>>(cnt, bscan, off, cur);
    k_scatter<<<(E + 255) / 256, 256, 0, stream>>>(row, col, E, dis, cur, csr_src, csr_w);

    dim3 g1((NITEM + 127) / 128, H1 / 128);   // 391 x 2
    k_gemm1<<<g1, 256, 0, stream>>>(features, Wt, b1, Hm);
    k_gemm2_norm<<<(NITEM + 3) / 4, 256, 0, stream>>>(Hm, W2, b2, out1);
    k_pref_norm<<<(NUSER + 3) / 4, 256, 0, stream>>>(pref, out1, out2);
    k_conv<<<(NNODE + 3) / 4, 256, 0, stream>>>(out1, off, cnt, csr_src, csr_w, h);
    k_conv_final<<<(NNODE + 3) / 4, 256, 0, stream>>>(h, off, cnt, csr_src, csr_w, out1);
}